// Round 12
// baseline (184.913 us; speedup 1.0000x reference)
//
#include <hip/hip_runtime.h>

#define NDESC 384
#define NTYPES 4
#define BLOCK_ATOMS 256
#define NTHREADS 384

typedef unsigned int uint32;
typedef unsigned long long u64;
typedef float f4 __attribute__((ext_vector_type(4)));

#define TAG_MASK 0xFFFF000000000000ull
#define TAG_VAL  0xA55A000000000000ull   // != 0x0000 (memset), != 0xAAAA (poison)

// tanh(x) = 1 - 2/(1+e^{2x}); native v_exp_f32 + v_rcp_f32. Abs err ~1e-6.
__device__ __forceinline__ float fast_tanh(float x) {
  float e = __builtin_amdgcn_exp2f(x * 2.8853900817779268f);   // e^{2x}
  return 1.0f - 2.0f * __builtin_amdgcn_rcpf(1.0f + e);
}

// Single fused kernel. Per-block histogram is published as one u64
// (4 x 9-bit counts + validity tag) with device-scope release; each block
// acquire-spins on all entries to build its stable scan. Safe: every block
// publishes BEFORE any wait (no cyclic dependency), and at this LDS/VGPR
// footprint all 512 blocks are co-resident (cap >= 4 blocks/CU).
__global__ __launch_bounds__(NTHREADS, 6) void main_kernel(
    const float* __restrict__ coords, const int* __restrict__ types,
    const float* __restrict__ W, u64* __restrict__ hist64,
    float* __restrict__ descOut, float* __restrict__ confOut,
    float* __restrict__ countsOut, int n, int nb) {
  __shared__ float sC[BLOCK_ATOMS][3];
  __shared__ f4 sRankData[BLOCK_ATOMS];      // rank -> {c0,c1,c2,pos}
  __shared__ uint32 waveCnt[BLOCK_ATOMS / 64][NTYPES];
  __shared__ uint32 sTot[NTYPES];
  __shared__ uint32 sOff[NTYPES];
  __shared__ uint32 sCum[NTYPES];

  int tid = threadIdx.x;
  int bid = blockIdx.x;
  int base = bid * BLOCK_ATOMS;

  // phase-C thread mapping, needed now for the early W loads
  int r = tid / 96;        // rank slot 0..3
  int c = tid - r * 96;    // 0..95
  int d0 = 4 * c;
  f4 W0 = *reinterpret_cast<const f4*>(W + d0);
  f4 W1 = *reinterpret_cast<const f4*>(W + NDESC + d0);
  f4 W2 = *reinterpret_cast<const f4*>(W + 2 * NDESC + d0);

  // stage this block's coords (256x3) coalesced
  for (int i = tid; i < BLOCK_ATOMS * 3; i += NTHREADS) {
    int g = base * 3 + i;
    sC[i / 3][i % 3] = (g < n * 3) ? coords[g] : 0.0f;
  }

  // ---- ballots: within-block per-wave counts + per-lane stable rank ----
  int idx = base + tid;
  int ty = -1;
  if (tid < BLOCK_ATOMS && idx < n) ty = types[idx];
  int wave = tid >> 6, lane = tid & 63;
  int myrank = 0;
  if (tid < BLOCK_ATOMS) {
    for (int t = 0; t < NTYPES; ++t) {
      u64 m = __ballot(ty == t);
      if (lane == 0) waveCnt[wave][t] = (uint32)__popcll(m);
      if (t == ty) myrank = (int)__popcll(m & ((1ull << lane) - 1ull));
    }
  }
  __syncthreads();

  // ---- publish own histogram entry (release, device scope) ----
  if (tid == 0) {
    u64 packed = TAG_VAL;
    for (int t = 0; t < NTYPES; ++t) {
      uint32 cnt = 0;
      for (int w = 0; w < BLOCK_ATOMS / 64; ++w) cnt += waveCnt[w][t];
      packed |= (u64)(cnt & 0x1FF) << (9 * t);
    }
    __hip_atomic_store(&hist64[bid], packed, __ATOMIC_RELEASE,
                       __HIP_MEMORY_SCOPE_AGENT);
  }

  // ---- spin-scan all block entries: wave t handles type t ----
  if (wave < NTYPES) {
    int t = wave;
    uint32 tot = 0, pre = 0;
    for (int b = lane; b < nb; b += 64) {
      u64 v;
      do {
        v = __hip_atomic_load(&hist64[b], __ATOMIC_ACQUIRE,
                              __HIP_MEMORY_SCOPE_AGENT);
      } while ((v & TAG_MASK) != TAG_VAL);
      uint32 h = (uint32)(v >> (9 * t)) & 0x1FF;
      tot += h;
      if (b < bid) pre += h;
    }
    for (int off = 32; off > 0; off >>= 1) {
      tot += __shfl_down(tot, off);
      pre += __shfl_down(pre, off);
    }
    if (lane == 0) { sTot[t] = tot; sOff[t] = pre; }
  }
  __syncthreads();
  if (tid == 0) {
    uint32 b = 0, cc = 0;
    for (int t = 0; t < NTYPES; ++t) {
      sOff[t] += b;
      b += sTot[t];
      uint32 cnt = 0;
      for (int w = 0; w < BLOCK_ATOMS / 64; ++w) cnt += waveCnt[w][t];
      sCum[t] = cc;
      cc += cnt;
    }
  }
  if (bid == 0 && tid < NTYPES) countsOut[tid] = (float)sTot[tid];
  __syncthreads();

  // ---- scatter packed rank data + conf ids ----
  if (tid < BLOCK_ATOMS && ty >= 0) {
    uint32 fullrank = (uint32)myrank;
    for (int w = 0; w < wave; ++w) fullrank += waveCnt[w][ty];
    uint32 pos = sOff[ty] + fullrank;
    uint32 brk = sCum[ty] + fullrank;   // rank within block, 0..valid-1
    f4 rd;
    rd.x = sC[tid][0];
    rd.y = sC[tid][1];
    rd.z = sC[tid][2];
    rd.w = __uint_as_float(pos);
    sRankData[brk] = rd;
    confOut[pos] = (float)(idx >> 6);   // idx / 64 atoms-per-conf
  }
  __syncthreads();

  // ---- phase C: rank order, 4 ranks x 96 threads, one b128 read/iter ----
  int valid = n - base;
  if (valid > BLOCK_ATOMS) valid = BLOCK_ATOMS;

  if (valid == BLOCK_ATOMS) {
#pragma unroll 4
    for (int k0 = 0; k0 < BLOCK_ATOMS; k0 += 4) {
      int k = k0 + r;
      f4 rd = sRankData[k];
      uint32 pos = __float_as_uint(rd.w);
      f4 v;
      v.x = fast_tanh(rd.x * W0.x + rd.y * W1.x + rd.z * W2.x);
      v.y = fast_tanh(rd.x * W0.y + rd.y * W1.y + rd.z * W2.y);
      v.z = fast_tanh(rd.x * W0.z + rd.y * W1.z + rd.z * W2.z);
      v.w = fast_tanh(rd.x * W0.w + rd.y * W1.w + rd.z * W2.w);
      *reinterpret_cast<f4*>(descOut + (size_t)pos * NDESC + d0) = v;
    }
  } else {
    for (int k0 = 0; k0 < BLOCK_ATOMS; k0 += 4) {
      int k = k0 + r;
      if (k < valid) {
        f4 rd = sRankData[k];
        uint32 pos = __float_as_uint(rd.w);
        f4 v;
        v.x = fast_tanh(rd.x * W0.x + rd.y * W1.x + rd.z * W2.x);
        v.y = fast_tanh(rd.x * W0.y + rd.y * W1.y + rd.z * W2.y);
        v.z = fast_tanh(rd.x * W0.z + rd.y * W1.z + rd.z * W2.z);
        v.w = fast_tanh(rd.x * W0.w + rd.y * W1.w + rd.z * W2.w);
        *reinterpret_cast<f4*>(descOut + (size_t)pos * NDESC + d0) = v;
      }
    }
  }
}

extern "C" void kernel_launch(void* const* d_in, const int* in_sizes, int n_in,
                              void* d_out, int out_size, void* d_ws, size_t ws_size,
                              hipStream_t stream) {
  const float* coords = (const float*)d_in[0];
  const int* types = (const int*)d_in[1];
  const float* W = (const float*)d_in[2];

  int n = in_sizes[1];                      // total atoms (= n_confs * 64)
  int nb = (n + BLOCK_ATOMS - 1) / BLOCK_ATOMS;

  u64* hist64 = (u64*)d_ws;                 // nb u64 entries (4 KB)

  float* descOut = (float*)d_out;
  float* confOut = descOut + (size_t)n * NDESC;
  float* countsOut = confOut + n;

  // clear flag area each call: tag 0 != TAG_VAL -> entries "not ready"
  hipMemsetAsync(hist64, 0, (size_t)nb * sizeof(u64), stream);
  hipLaunchKernelGGL(main_kernel, dim3(nb), dim3(NTHREADS), 0, stream,
                     coords, types, W, hist64, descOut, confOut, countsOut,
                     n, nb);
}

// Round 13
// 46.135 us; speedup vs baseline: 4.0081x; 4.0081x over previous
//
#include <hip/hip_runtime.h>

#define NDESC 384
#define NTYPES 4
#define BLOCK_ATOMS 256
#define NTHREADS 384

typedef unsigned int uint32;
typedef unsigned long long u64;
typedef float f4 __attribute__((ext_vector_type(4)));

// tanh(x) = 1 - 2/(1+e^{2x}); native v_exp_f32 + v_rcp_f32. Abs err ~1e-6.
__device__ __forceinline__ float fast_tanh(float x) {
  float e = __builtin_amdgcn_exp2f(x * 2.8853900817779268f);   // e^{2x}
  return 1.0f - 2.0f * __builtin_amdgcn_rcpf(1.0f + e);
}

// ---------------- Kernel 1: per-block type histogram (ballot-based) --------
__global__ __launch_bounds__(BLOCK_ATOMS) void hist_kernel(
    const int* __restrict__ types, uint32* __restrict__ blockHist, int n) {
  __shared__ uint32 waveCnt[BLOCK_ATOMS / 64][NTYPES];
  int tid = threadIdx.x;
  int idx = blockIdx.x * BLOCK_ATOMS + tid;
  int ty = (idx < n) ? types[idx] : -1;
  int wave = tid >> 6, lane = tid & 63;
  for (int t = 0; t < NTYPES; ++t) {
    u64 m = __ballot(ty == t);
    if (lane == 0) waveCnt[wave][t] = (uint32)__popcll(m);
  }
  __syncthreads();
  if (tid < NTYPES) {
    uint32 s = 0;
    for (int w = 0; w < BLOCK_ATOMS / 64; ++w) s += waveCnt[w][tid];
    blockHist[blockIdx.x * NTYPES + tid] = s;
  }
}

// ---------------- Kernel 2: fused scan + rank + descriptor + scatter -------
// Phase C batches 16 independent store payloads in registers (statically
// indexed, fully unrolled) before issuing 16 stores back-to-back: deepens
// outstanding-store count per wave (vmcnt) ~4x vs register-recycled unroll-4.
__global__ __launch_bounds__(NTHREADS, 4) void main_kernel(
    const float* __restrict__ coords, const int* __restrict__ types,
    const float* __restrict__ W, const uint32* __restrict__ blockHist,
    float* __restrict__ descOut, float* __restrict__ confOut,
    float* __restrict__ countsOut, int n, int nb) {
  __shared__ float sC[BLOCK_ATOMS][3];
  __shared__ f4 sRankData[BLOCK_ATOMS];      // rank -> {c0,c1,c2,pos}
  __shared__ uint32 waveCnt[BLOCK_ATOMS / 64][NTYPES];
  __shared__ uint32 sTot[NTYPES];
  __shared__ uint32 sOff[NTYPES];
  __shared__ uint32 sCum[NTYPES];

  int tid = threadIdx.x;
  int bid = blockIdx.x;
  int base = bid * BLOCK_ATOMS;

  int r = tid / 96;        // rank slot 0..3
  int c = tid - r * 96;    // 0..95
  int d0 = 4 * c;
  f4 W0 = *reinterpret_cast<const f4*>(W + d0);
  f4 W1 = *reinterpret_cast<const f4*>(W + NDESC + d0);
  f4 W2 = *reinterpret_cast<const f4*>(W + 2 * NDESC + d0);

  for (int i = tid; i < BLOCK_ATOMS * 3; i += NTHREADS) {
    int g = base * 3 + i;
    sC[i / 3][i % 3] = (g < n * 3) ? coords[g] : 0.0f;
  }

  // ---- ballots: within-block per-wave counts + per-lane stable rank ----
  int idx = base + tid;
  int ty = -1;
  if (tid < BLOCK_ATOMS && idx < n) ty = types[idx];
  int wave = tid >> 6, lane = tid & 63;
  int myrank = 0;
  if (tid < BLOCK_ATOMS) {
    for (int t = 0; t < NTYPES; ++t) {
      u64 m = __ballot(ty == t);
      if (lane == 0) waveCnt[wave][t] = (uint32)__popcll(m);
      if (t == ty) myrank = (int)__popcll(m & ((1ull << lane) - 1ull));
    }
  }

  // ---- per-block scan of blockHist: wave t handles type t ----
  if (wave < NTYPES) {
    int t = wave;
    uint32 tot = 0, pre = 0;
    for (int b = lane; b < nb; b += 64) {
      uint32 h = blockHist[b * NTYPES + t];
      tot += h;
      if (b < bid) pre += h;
    }
    for (int off = 32; off > 0; off >>= 1) {
      tot += __shfl_down(tot, off);
      pre += __shfl_down(pre, off);
    }
    if (lane == 0) { sTot[t] = tot; sOff[t] = pre; }
  }
  __syncthreads();
  if (tid == 0) {
    uint32 b = 0, cc = 0;
    for (int t = 0; t < NTYPES; ++t) {
      sOff[t] += b;
      b += sTot[t];
      uint32 cnt = 0;
      for (int w = 0; w < BLOCK_ATOMS / 64; ++w) cnt += waveCnt[w][t];
      sCum[t] = cc;
      cc += cnt;
    }
  }
  if (bid == 0 && tid < NTYPES) countsOut[tid] = (float)sTot[tid];
  __syncthreads();

  // ---- scatter packed rank data + conf ids ----
  if (tid < BLOCK_ATOMS && ty >= 0) {
    uint32 fullrank = (uint32)myrank;
    for (int w = 0; w < wave; ++w) fullrank += waveCnt[w][ty];
    uint32 pos = sOff[ty] + fullrank;
    uint32 brk = sCum[ty] + fullrank;
    f4 rd;
    rd.x = sC[tid][0];
    rd.y = sC[tid][1];
    rd.z = sC[tid][2];
    rd.w = __uint_as_float(pos);
    sRankData[brk] = rd;
    confOut[pos] = (float)(idx >> 6);   // idx / 64 atoms-per-conf
  }
  __syncthreads();

  // ---- phase C: 4 batches x 16 payloads, then 16 stores back-to-back ----
  int valid = n - base;
  if (valid > BLOCK_ATOMS) valid = BLOCK_ATOMS;

  if (valid == BLOCK_ATOMS) {
    for (int batch = 0; batch < BLOCK_ATOMS / 64; ++batch) {
      f4 vals[16];
      uint32 poss[16];
#pragma unroll
      for (int u = 0; u < 16; ++u) {
        int k = batch * 64 + u * 4 + r;
        f4 rd = sRankData[k];
        poss[u] = __float_as_uint(rd.w);
        f4 v;
        v.x = fast_tanh(rd.x * W0.x + rd.y * W1.x + rd.z * W2.x);
        v.y = fast_tanh(rd.x * W0.y + rd.y * W1.y + rd.z * W2.y);
        v.z = fast_tanh(rd.x * W0.z + rd.y * W1.z + rd.z * W2.z);
        v.w = fast_tanh(rd.x * W0.w + rd.y * W1.w + rd.z * W2.w);
        vals[u] = v;
      }
#pragma unroll
      for (int u = 0; u < 16; ++u) {
        *reinterpret_cast<f4*>(descOut + (size_t)poss[u] * NDESC + d0) =
            vals[u];
      }
    }
  } else {
    for (int k0 = 0; k0 < BLOCK_ATOMS; k0 += 4) {
      int k = k0 + r;
      if (k < valid) {
        f4 rd = sRankData[k];
        uint32 pos = __float_as_uint(rd.w);
        f4 v;
        v.x = fast_tanh(rd.x * W0.x + rd.y * W1.x + rd.z * W2.x);
        v.y = fast_tanh(rd.x * W0.y + rd.y * W1.y + rd.z * W2.y);
        v.z = fast_tanh(rd.x * W0.z + rd.y * W1.z + rd.z * W2.z);
        v.w = fast_tanh(rd.x * W0.w + rd.y * W1.w + rd.z * W2.w);
        *reinterpret_cast<f4*>(descOut + (size_t)pos * NDESC + d0) = v;
      }
    }
  }
}

extern "C" void kernel_launch(void* const* d_in, const int* in_sizes, int n_in,
                              void* d_out, int out_size, void* d_ws, size_t ws_size,
                              hipStream_t stream) {
  const float* coords = (const float*)d_in[0];
  const int* types = (const int*)d_in[1];
  const float* W = (const float*)d_in[2];

  int n = in_sizes[1];                      // total atoms (= n_confs * 64)
  int nb = (n + BLOCK_ATOMS - 1) / BLOCK_ATOMS;

  uint32* blockHist = (uint32*)d_ws;        // nb * 4 uints

  float* descOut = (float*)d_out;
  float* confOut = descOut + (size_t)n * NDESC;
  float* countsOut = confOut + n;

  hipLaunchKernelGGL(hist_kernel, dim3(nb), dim3(BLOCK_ATOMS), 0, stream,
                     types, blockHist, n);
  hipLaunchKernelGGL(main_kernel, dim3(nb), dim3(NTHREADS), 0, stream,
                     coords, types, W, blockHist, descOut, confOut, countsOut,
                     n, nb);
}